// Round 6
// baseline (436417.529 us; speedup 1.0000x reference)
//
#include <hip/hip_runtime.h>

namespace {

constexpr int B = 128;
constexpr int T = 1024;
constexpr int DIN = 48;
constexpr int H = 256;
constexpr int G = 4 * H;          // 1024 gate rows per direction
constexpr int NT = 512;           // threads per block: 16 k-slices x 32 row-quads

constexpr size_t BH           = (size_t)B * H;                       // 32768
constexpr size_t WT_FLOATS    = 4 * 256 * 1024 + 2 * 48 * 1024 + 2 * 512 * 1024; // 2,195,456
constexpr size_t STATE_FLOATS = 12 * BH;                             // 393,216
constexpr size_t FLAG_INTS    = 8192;                                // 32 grp x 8 members x 16 + barrier
constexpr size_t O0_ELEMS     = (size_t)B * T * 512;                 // 67,108,864

__device__ __forceinline__ float sigmoidf_(float x) {
    float z = __expf(-fabsf(x));
    float s = 1.0f / (1.0f + z);
    return x >= 0.0f ? s : 1.0f - s;
}
__device__ __forceinline__ float tanhf_(float x) {
    float z = __expf(-2.0f * fabsf(x));
    float tp = (1.0f - z) / (1.0f + z);
    return x >= 0.0f ? tp : -tp;
}
__device__ __forceinline__ float bf2f(unsigned short s) {
    union { unsigned int u; float f; } v; v.u = ((unsigned int)s) << 16; return v.f;
}
__device__ __forceinline__ unsigned short f2bf(float f) {
    union { float f; unsigned int u; } v; v.f = f;
    unsigned int u = v.u;
    return (unsigned short)((u + 0x7FFFu + ((u >> 16) & 1u)) >> 16);  // RNE
}
__device__ __forceinline__ float fcomp(float4 v, int j) {
    return (j == 0) ? v.x : (j == 1) ? v.y : (j == 2) ? v.z : v.w;
}

__global__ void zero_f(float* __restrict__ p, int n) {
    int i = blockIdx.x * blockDim.x + threadIdx.x;
    if (i < n) p[i] = 0.0f;
}

// dst[k][r] = src[r][k], src is [1024][K]; output-coalesced
__global__ void transpose_w(const float* __restrict__ src, float* __restrict__ dst, int K) {
    int idx = blockIdx.x * blockDim.x + threadIdx.x;
    if (idx >= K * 1024) return;
    int r = idx & 1023;
    int k = idx >> 10;
    dst[idx] = src[r * K + k];
}

// Persistent, weight-stationary LSTM v2.
// 256 blocks x 512 threads, 1 block/CU (8 waves, 2/SIMD), VGPR capped at 256
// via __launch_bounds__(512,2). Thread = (ks 0..15, rq 0..31).
// Per-thread register weights: L0 = 19 float4 (x:3, h:16), L1 = 48 float4
// (x:32, h:16). Batch-split into 2 passes of 4 so acc is 16 regs, pass-scoped.
// Peak live ~233 VGPR -> no spill (round-5 failure mode was 456 demanded @256 cap).
// Sync: per-member flag slots (store-only publish, poll 8), one grid barrier
// between layers. h/O0 coherence identical to the passing round-4/5 kernels.
template<typename OT>
__global__ __launch_bounds__(NT, 2)
void lstm_persist(const float* __restrict__ x,
    const float* __restrict__ wih0f, const float* __restrict__ wih0b,
    const float* __restrict__ whh0f, const float* __restrict__ whh0b,
    const float* __restrict__ bih0f, const float* __restrict__ bhh0f,
    const float* __restrict__ bih0b, const float* __restrict__ bhh0b,
    const float* __restrict__ wih1f, const float* __restrict__ wih1b,
    const float* __restrict__ whh1f, const float* __restrict__ whh1b,
    const float* __restrict__ bih1f, const float* __restrict__ bhh1f,
    const float* __restrict__ bih1b, const float* __restrict__ bhh1b,
    float* __restrict__ h_l0, float* __restrict__ h_l1,
    float* __restrict__ c_l0, float* __restrict__ c_l1,
    OT* __restrict__ O0, const int* __restrict__ lengths, int* __restrict__ flags)
{
    const int bx  = blockIdx.x;
    const int d   = bx >> 7;                 // 0 fwd, 1 bwd
    const int rem = bx & 127;
    const int b0  = (rem >> 3) * 8;
    const int c0  = (rem & 7) * 32;
    const int tid = threadIdx.x;
    const int ks  = tid & 15;                // 16 k-slices
    const int rq  = tid >> 4;                // 32 row-quads

    const int grp = d * 16 + (rem >> 3);     // sync group (dir, batch-tile): 8 members
    int* grpflags = flags + grp * 8 * 16;
    int* myflag   = grpflags + (rem & 7) * 16;

    const int gate  = rq >> 3;               // gate-major local rows
    const int chl4  = (rq & 7) << 2;
    const int grow0 = gate * 256 + c0 + chl4;    // global gate-row of acc[0] (f4-aligned)

    // gate-math mapping (first 256 threads active)
    const int gm_chl = tid & 31;
    const int gm_b   = (tid >> 5) & 7;       // &7: avoid OOB lengths read for tid>=256
    const int gm_gch = c0 + gm_chl;
    const int my_len = lengths[b0 + gm_b];

    // LDS layouts chosen for conflict-free 16-lane reads:
    //  x4: [b][kk2(8)][ks(16)] stride_b=132 -> read addrs consecutive in ks
    //  h4: [b][kk2(4)][ks(16)] stride_b=68
    __shared__ float  lds_x0[8 * 52];
    __shared__ float4 lds_x4[8 * 132];
    __shared__ float4 lds_h4[8 * 68];
    __shared__ float  lds_g[128 * 9];

    // ======================= phase 0: layer 0 =======================
    {
        const float* wih_t = d ? wih0b : wih0f;  // [48][1024]
        const float* whh_t = d ? whh0b : whh0f;  // [256][1024]
        const float* bih   = d ? bih0b : bih0f;
        const float* bhh   = d ? bhh0b : bhh0f;
        float* crow = c_l0 + d * (B * H);
        const float gm_bi[4] = { bih[0*256+gm_gch] + bhh[0*256+gm_gch],
                                 bih[1*256+gm_gch] + bhh[1*256+gm_gch],
                                 bih[2*256+gm_gch] + bhh[2*256+gm_gch],
                                 bih[3*256+gm_gch] + bhh[3*256+gm_gch] };

        // ---- weights -> VGPRs (once): 3 + 16 float4 ----
        float4 w0x[3], w0h[16];
        #pragma unroll
        for (int kk = 0; kk < 3; kk++)
            w0x[kk] = *(const float4*)(wih_t + (ks * 3 + kk) * G + grow0);
        #pragma unroll
        for (int kk = 0; kk < 16; kk++)
            w0h[kk] = *(const float4*)(whh_t + (ks * 16 + kk) * G + grow0);

        #pragma unroll 1
        for (int s = 0; s < T; ++s) {
            const int t = d ? (T - 1 - s) : s;
            const float* hrow_in  = h_l0 + ((size_t)((s & 1) * 2 + d)) * (B * H);
            float*       hrow_out = h_l0 + ((size_t)(((s & 1) ^ 1) * 2 + d)) * (B * H);

            // ---- stage x tile (8 x 48 scalars) ----
            if (tid < 384) {
                int b = tid / 48, k = tid - b * 48;
                lds_x0[b * 52 + k] = x[((size_t)(b0 + b) * T + t) * DIN + k];
            }
            __syncthreads();

            float acc[4][4];
            #pragma unroll
            for (int i = 0; i < 4; i++)
                #pragma unroll
                for (int bl = 0; bl < 4; bl++) acc[i][bl] = 0.0f;

            // ---- pass0 x-part (batches 0..3) BEFORE peer-wait ----
            #pragma unroll
            for (int kk = 0; kk < 3; kk++) {
                float4 w4 = w0x[kk];
                #pragma unroll
                for (int bl = 0; bl < 4; bl++) {
                    float xs = lds_x0[bl * 52 + ks * 3 + kk];
                    acc[0][bl] = fmaf(w4.x, xs, acc[0][bl]);
                    acc[1][bl] = fmaf(w4.y, xs, acc[1][bl]);
                    acc[2][bl] = fmaf(w4.z, xs, acc[2][bl]);
                    acc[3][bl] = fmaf(w4.w, xs, acc[3][bl]);
                }
            }

            // ---- wait: all 8 peers published step s-1 ----
            if (tid == 0) {
                for (;;) {
                    bool ready = true;
                    #pragma unroll
                    for (int m = 0; m < 8; m++)
                        ready &= (__hip_atomic_load(&grpflags[m * 16], __ATOMIC_RELAXED, __HIP_MEMORY_SCOPE_AGENT) >= s);
                    if (ready) break;
                    __builtin_amdgcn_s_sleep(2);
                }
            }
            __syncthreads();

            // ---- stage h (agent loads) ----
            #pragma unroll 1
            for (int i = tid; i < 8 * 256; i += NT) {
                int b = i >> 8, k = i & 255;
                float v = __hip_atomic_load(hrow_in + (b0 + b) * H + k,
                                            __ATOMIC_RELAXED, __HIP_MEMORY_SCOPE_AGENT);
                ((float*)lds_h4)[(b * 68 + ((k >> 2) & 3) * 16 + (k >> 4)) * 4 + (k & 3)] = v;
            }
            __syncthreads();

            // ---- pass0 h-part + reduce ----
            #pragma unroll
            for (int kk2 = 0; kk2 < 4; kk2++) {
                #pragma unroll
                for (int bl = 0; bl < 4; bl++) {
                    float4 hv = lds_h4[bl * 68 + kk2 * 16 + ks];
                    #pragma unroll
                    for (int j = 0; j < 4; j++) {
                        float4 w4 = w0h[kk2 * 4 + j];
                        float hs = fcomp(hv, j);
                        acc[0][bl] = fmaf(w4.x, hs, acc[0][bl]);
                        acc[1][bl] = fmaf(w4.y, hs, acc[1][bl]);
                        acc[2][bl] = fmaf(w4.z, hs, acc[2][bl]);
                        acc[3][bl] = fmaf(w4.w, hs, acc[3][bl]);
                    }
                }
            }
            #pragma unroll
            for (int i = 0; i < 4; i++)
                #pragma unroll
                for (int bl = 0; bl < 4; bl++) {
                    float v = acc[i][bl];
                    v += __shfl_xor(v, 1, 64);
                    v += __shfl_xor(v, 2, 64);
                    v += __shfl_xor(v, 4, 64);
                    v += __shfl_xor(v, 8, 64);
                    if (ks == 0) lds_g[(rq * 4 + i) * 9 + bl] = v;
                }

            // ---- pass1 (batches 4..7) ----
            #pragma unroll
            for (int i = 0; i < 4; i++)
                #pragma unroll
                for (int bl = 0; bl < 4; bl++) acc[i][bl] = 0.0f;
            #pragma unroll
            for (int kk = 0; kk < 3; kk++) {
                float4 w4 = w0x[kk];
                #pragma unroll
                for (int bl = 0; bl < 4; bl++) {
                    float xs = lds_x0[(4 + bl) * 52 + ks * 3 + kk];
                    acc[0][bl] = fmaf(w4.x, xs, acc[0][bl]);
                    acc[1][bl] = fmaf(w4.y, xs, acc[1][bl]);
                    acc[2][bl] = fmaf(w4.z, xs, acc[2][bl]);
                    acc[3][bl] = fmaf(w4.w, xs, acc[3][bl]);
                }
            }
            #pragma unroll
            for (int kk2 = 0; kk2 < 4; kk2++) {
                #pragma unroll
                for (int bl = 0; bl < 4; bl++) {
                    float4 hv = lds_h4[(4 + bl) * 68 + kk2 * 16 + ks];
                    #pragma unroll
                    for (int j = 0; j < 4; j++) {
                        float4 w4 = w0h[kk2 * 4 + j];
                        float hs = fcomp(hv, j);
                        acc[0][bl] = fmaf(w4.x, hs, acc[0][bl]);
                        acc[1][bl] = fmaf(w4.y, hs, acc[1][bl]);
                        acc[2][bl] = fmaf(w4.z, hs, acc[2][bl]);
                        acc[3][bl] = fmaf(w4.w, hs, acc[3][bl]);
                    }
                }
            }
            #pragma unroll
            for (int i = 0; i < 4; i++)
                #pragma unroll
                for (int bl = 0; bl < 4; bl++) {
                    float v = acc[i][bl];
                    v += __shfl_xor(v, 1, 64);
                    v += __shfl_xor(v, 2, 64);
                    v += __shfl_xor(v, 4, 64);
                    v += __shfl_xor(v, 8, 64);
                    if (ks == 0) lds_g[(rq * 4 + i) * 9 + 4 + bl] = v;
                }
            __syncthreads();

            // ---- gate math (first 256 threads) ----
            if (tid < 256) {
                float gi = lds_g[(0 * 32 + gm_chl) * 9 + gm_b] + gm_bi[0];
                float gf = lds_g[(1 * 32 + gm_chl) * 9 + gm_b] + gm_bi[1];
                float gg = lds_g[(2 * 32 + gm_chl) * 9 + gm_b] + gm_bi[2];
                float go = lds_g[(3 * 32 + gm_chl) * 9 + gm_b] + gm_bi[3];
                float iv = sigmoidf_(gi);
                float fv = sigmoidf_(gf);
                float gv = tanhf_(gg);
                float ov = sigmoidf_(go);
                const int sidx = (b0 + gm_b) * H + gm_gch;
                float c_old = crow[sidx];
                float h_old = ((float*)lds_h4)[(gm_b * 68 + ((gm_gch >> 2) & 3) * 16 + (gm_gch >> 4)) * 4 + (gm_gch & 3)];
                float c_new = fv * c_old + iv * gv;
                float h_new = ov * tanhf_(c_new);
                bool valid = t < my_len;
                if (valid) crow[sidx] = c_new;
                __hip_atomic_store(hrow_out + sidx, valid ? h_new : h_old,
                                   __ATOMIC_RELAXED, __HIP_MEMORY_SCOPE_AGENT);
                float hv_o = valid ? h_new : 0.0f;
                size_t oidx = ((size_t)(b0 + gm_b) * T + t) * 512 + d * 256 + gm_gch;
                if constexpr (sizeof(OT) == 4)
                    __hip_atomic_store(O0 + oidx, hv_o, __ATOMIC_RELAXED, __HIP_MEMORY_SCOPE_AGENT);
                else
                    __hip_atomic_store(O0 + oidx, f2bf(hv_o), __ATOMIC_RELAXED, __HIP_MEMORY_SCOPE_AGENT);
            }
            __syncthreads();   // drain h/O0 stores before publish
            if (tid == 0)
                __hip_atomic_store(myflag, s + 1, __ATOMIC_RELAXED, __HIP_MEMORY_SCOPE_AGENT);
        }
    }

    // ======================= grid-wide phase barrier =======================
    __syncthreads();
    if (tid == 0) {
        __threadfence();
        __hip_atomic_fetch_add(&flags[32 * 8 * 16], 1, __ATOMIC_ACQ_REL, __HIP_MEMORY_SCOPE_AGENT);
        while (__hip_atomic_load(&flags[32 * 8 * 16], __ATOMIC_ACQUIRE, __HIP_MEMORY_SCOPE_AGENT) < 256)
            __builtin_amdgcn_s_sleep(2);
        __threadfence();
    }
    __syncthreads();

    // ======================= phase 1: layer 1 =======================
    {
        const float* wih_t = d ? wih1b : wih1f;  // [512][1024]
        const float* whh_t = d ? whh1b : whh1f;  // [256][1024]
        const float* bih   = d ? bih1b : bih1f;
        const float* bhh   = d ? bhh1b : bhh1f;
        float* crow = c_l1 + d * (B * H);
        const float gm_bi[4] = { bih[0*256+gm_gch] + bhh[0*256+gm_gch],
                                 bih[1*256+gm_gch] + bhh[1*256+gm_gch],
                                 bih[2*256+gm_gch] + bhh[2*256+gm_gch],
                                 bih[3*256+gm_gch] + bhh[3*256+gm_gch] };

        // ---- weights -> VGPRs (once): 32 + 16 float4 = 192 VGPRs ----
        float4 w1x[32], w1h[16];
        #pragma unroll
        for (int kk = 0; kk < 32; kk++)
            w1x[kk] = *(const float4*)(wih_t + (ks * 32 + kk) * G + grow0);
        #pragma unroll
        for (int kk = 0; kk < 16; kk++)
            w1h[kk] = *(const float4*)(whh_t + (ks * 16 + kk) * G + grow0);

        #pragma unroll 1
        for (int s = 0; s < T; ++s) {
            const int t = d ? (T - 1 - s) : s;
            const float* hrow_in  = h_l1 + ((size_t)((s & 1) * 2 + d)) * (B * H);
            float*       hrow_out = h_l1 + ((size_t)(((s & 1) ^ 1) * 2 + d)) * (B * H);

            // ---- stage x tile from O0 (1024 f4, 2/thread) ----
            #pragma unroll
            for (int ii = 0; ii < 2; ii++) {
                int i = tid + ii * NT;
                int b = i >> 7, kq = i & 127;
                float4 v;
                if constexpr (sizeof(OT) == 4) {
                    v = *(const float4*)((const float*)O0 + ((size_t)(b0 + b) * T + t) * 512 + kq * 4);
                } else {
                    ushort4 uv = *(const ushort4*)((const unsigned short*)O0 + ((size_t)(b0 + b) * T + t) * 512 + kq * 4);
                    v = make_float4(bf2f(uv.x), bf2f(uv.y), bf2f(uv.z), bf2f(uv.w));
                }
                lds_x4[b * 132 + (kq & 7) * 16 + (kq >> 3)] = v;
            }
            __syncthreads();

            float acc[4][4];
            #pragma unroll
            for (int i = 0; i < 4; i++)
                #pragma unroll
                for (int bl = 0; bl < 4; bl++) acc[i][bl] = 0.0f;

            // ---- pass0 x-part (batches 0..3) BEFORE peer-wait ----
            #pragma unroll
            for (int kk2 = 0; kk2 < 8; kk2++) {
                #pragma unroll
                for (int bl = 0; bl < 4; bl++) {
                    float4 xv = lds_x4[bl * 132 + kk2 * 16 + ks];
                    #pragma unroll
                    for (int j = 0; j < 4; j++) {
                        float4 w4 = w1x[kk2 * 4 + j];
                        float xs = fcomp(xv, j);
                        acc[0][bl] = fmaf(w4.x, xs, acc[0][bl]);
                        acc[1][bl] = fmaf(w4.y, xs, acc[1][bl]);
                        acc[2][bl] = fmaf(w4.z, xs, acc[2][bl]);
                        acc[3][bl] = fmaf(w4.w, xs, acc[3][bl]);
                    }
                }
            }

            // ---- wait: all 8 peers >= T + s ----
            if (tid == 0) {
                const int target = T + s;
                for (;;) {
                    bool ready = true;
                    #pragma unroll
                    for (int m = 0; m < 8; m++)
                        ready &= (__hip_atomic_load(&grpflags[m * 16], __ATOMIC_RELAXED, __HIP_MEMORY_SCOPE_AGENT) >= target);
                    if (ready) break;
                    __builtin_amdgcn_s_sleep(2);
                }
            }
            __syncthreads();

            // ---- stage h ----
            #pragma unroll 1
            for (int i = tid; i < 8 * 256; i += NT) {
                int b = i >> 8, k = i & 255;
                float v = __hip_atomic_load(hrow_in + (b0 + b) * H + k,
                                            __ATOMIC_RELAXED, __HIP_MEMORY_SCOPE_AGENT);
                ((float*)lds_h4)[(b * 68 + ((k >> 2) & 3) * 16 + (k >> 4)) * 4 + (k & 3)] = v;
            }
            __syncthreads();

            // ---- pass0 h-part + reduce ----
            #pragma unroll
            for (int kk2 = 0; kk2 < 4; kk2++) {
                #pragma unroll
                for (int bl = 0; bl < 4; bl++) {
                    float4 hv = lds_h4[bl * 68 + kk2 * 16 + ks];
                    #pragma unroll
                    for (int j = 0; j < 4; j++) {
                        float4 w4 = w1h[kk2 * 4 + j];
                        float hs = fcomp(hv, j);
                        acc[0][bl] = fmaf(w4.x, hs, acc[0][bl]);
                        acc[1][bl] = fmaf(w4.y, hs, acc[1][bl]);
                        acc[2][bl] = fmaf(w4.z, hs, acc[2][bl]);
                        acc[3][bl] = fmaf(w4.w, hs, acc[3][bl]);
                    }
                }
            }
            #pragma unroll
            for (int i = 0; i < 4; i++)
                #pragma unroll
                for (int bl = 0; bl < 4; bl++) {
                    float v = acc[i][bl];
                    v += __shfl_xor(v, 1, 64);
                    v += __shfl_xor(v, 2, 64);
                    v += __shfl_xor(v, 4, 64);
                    v += __shfl_xor(v, 8, 64);
                    if (ks == 0) lds_g[(rq * 4 + i) * 9 + bl] = v;
                }

            // ---- pass1 (batches 4..7) ----
            #pragma unroll
            for (int i = 0; i < 4; i++)
                #pragma unroll
                for (int bl = 0; bl < 4; bl++) acc[i][bl] = 0.0f;
            #pragma unroll
            for (int kk2 = 0; kk2 < 8; kk2++) {
                #pragma unroll
                for (int bl = 0; bl < 4; bl++) {
                    float4 xv = lds_x4[(4 + bl) * 132 + kk2 * 16 + ks];
                    #pragma unroll
                    for (int j = 0; j < 4; j++) {
                        float4 w4 = w1x[kk2 * 4 + j];
                        float xs = fcomp(xv, j);
                        acc[0][bl] = fmaf(w4.x, xs, acc[0][bl]);
                        acc[1][bl] = fmaf(w4.y, xs, acc[1][bl]);
                        acc[2][bl] = fmaf(w4.z, xs, acc[2][bl]);
                        acc[3][bl] = fmaf(w4.w, xs, acc[3][bl]);
                    }
                }
            }
            #pragma unroll
            for (int kk2 = 0; kk2 < 4; kk2++) {
                #pragma unroll
                for (int bl = 0; bl < 4; bl++) {
                    float4 hv = lds_h4[(4 + bl) * 68 + kk2 * 16 + ks];
                    #pragma unroll
                    for (int j = 0; j < 4; j++) {
                        float4 w4 = w1h[kk2 * 4 + j];
                        float hs = fcomp(hv, j);
                        acc[0][bl] = fmaf(w4.x, hs, acc[0][bl]);
                        acc[1][bl] = fmaf(w4.y, hs, acc[1][bl]);
                        acc[2][bl] = fmaf(w4.z, hs, acc[2][bl]);
                        acc[3][bl] = fmaf(w4.w, hs, acc[3][bl]);
                    }
                }
            }
            #pragma unroll
            for (int i = 0; i < 4; i++)
                #pragma unroll
                for (int bl = 0; bl < 4; bl++) {
                    float v = acc[i][bl];
                    v += __shfl_xor(v, 1, 64);
                    v += __shfl_xor(v, 2, 64);
                    v += __shfl_xor(v, 4, 64);
                    v += __shfl_xor(v, 8, 64);
                    if (ks == 0) lds_g[(rq * 4 + i) * 9 + 4 + bl] = v;
                }
            __syncthreads();

            // ---- gate math ----
            if (tid < 256) {
                float gi = lds_g[(0 * 32 + gm_chl) * 9 + gm_b] + gm_bi[0];
                float gf = lds_g[(1 * 32 + gm_chl) * 9 + gm_b] + gm_bi[1];
                float gg = lds_g[(2 * 32 + gm_chl) * 9 + gm_b] + gm_bi[2];
                float go = lds_g[(3 * 32 + gm_chl) * 9 + gm_b] + gm_bi[3];
                float iv = sigmoidf_(gi);
                float fv = sigmoidf_(gf);
                float gv = tanhf_(gg);
                float ov = sigmoidf_(go);
                const int sidx = (b0 + gm_b) * H + gm_gch;
                float c_old = crow[sidx];
                float h_old = ((float*)lds_h4)[(gm_b * 68 + ((gm_gch >> 2) & 3) * 16 + (gm_gch >> 4)) * 4 + (gm_gch & 3)];
                float c_new = fv * c_old + iv * gv;
                float h_new = ov * tanhf_(c_new);
                bool valid = t < my_len;
                if (valid) crow[sidx] = c_new;
                __hip_atomic_store(hrow_out + sidx, valid ? h_new : h_old,
                                   __ATOMIC_RELAXED, __HIP_MEMORY_SCOPE_AGENT);
            }
            __syncthreads();
            if (tid == 0)
                __hip_atomic_store(myflag, T + s + 1, __ATOMIC_RELAXED, __HIP_MEMORY_SCOPE_AGENT);
        }
    }
}

__global__ __launch_bounds__(256)
void fc_head(const float* __restrict__ h1,   // [2][B][H] final layer-1 h (parity 0)
             const float* __restrict__ fc1w, const float* __restrict__ fc1b,
             const float* __restrict__ fc2w, const float* __restrict__ fc2b,
             float* __restrict__ out)
{
    int b = blockIdx.x;
    int tid = threadIdx.x;
    __shared__ float hid[512];
    __shared__ float red[4];
    hid[tid]       = h1[b * H + tid];
    hid[256 + tid] = h1[(size_t)B * H + b * H + tid];
    __syncthreads();
    float a = fc1b[tid];
    const float4* w4 = (const float4*)(fc1w + tid * 512);
    const float4* h4 = (const float4*)hid;
    #pragma unroll 4
    for (int k = 0; k < 128; k++) {
        float4 w = w4[k], h = h4[k];
        a = fmaf(w.x, h.x, a); a = fmaf(w.y, h.y, a);
        a = fmaf(w.z, h.z, a); a = fmaf(w.w, h.w, a);
    }
    float r = fmaxf(a, 0.0f);
    float v = r * fc2w[tid];
    #pragma unroll
    for (int off = 32; off > 0; off >>= 1) v += __shfl_down(v, off, 64);
    if ((tid & 63) == 0) red[tid >> 6] = v;
    __syncthreads();
    if (tid == 0) out[b] = red[0] + red[1] + red[2] + red[3] + fc2b[0];
}

} // namespace

extern "C" void kernel_launch(void* const* d_in, const int* in_sizes, int n_in,
                              void* d_out, int out_size, void* d_ws, size_t ws_size,
                              hipStream_t stream)
{
    const float* x        = (const float*)d_in[0];
    const int*   lengths  = (const int*)d_in[1];
    const float* w_ih_l0f = (const float*)d_in[2];
    const float* w_hh_l0f = (const float*)d_in[3];
    const float* b_ih_l0f = (const float*)d_in[4];
    const float* b_hh_l0f = (const float*)d_in[5];
    const float* w_ih_l0b = (const float*)d_in[6];
    const float* w_hh_l0b = (const float*)d_in[7];
    const float* b_ih_l0b = (const float*)d_in[8];
    const float* b_hh_l0b = (const float*)d_in[9];
    const float* w_ih_l1f = (const float*)d_in[10];
    const float* w_hh_l1f = (const float*)d_in[11];
    const float* b_ih_l1f = (const float*)d_in[12];
    const float* b_hh_l1f = (const float*)d_in[13];
    const float* w_ih_l1b = (const float*)d_in[14];
    const float* w_hh_l1b = (const float*)d_in[15];
    const float* b_ih_l1b = (const float*)d_in[16];
    const float* b_hh_l1b = (const float*)d_in[17];
    const float* fc1w     = (const float*)d_in[18];
    const float* fc1b     = (const float*)d_in[19];
    const float* fc2w     = (const float*)d_in[20];
    const float* fc2b     = (const float*)d_in[21];

    float* ws = (float*)d_ws;

    // ---- workspace layout: [weights | state | flags | O0] ----
    float* whh_t_l0f = ws;
    float* whh_t_l0b = whh_t_l0f + 256 * 1024;
    float* whh_t_l1f = whh_t_l0b + 256 * 1024;
    float* whh_t_l1b = whh_t_l1f + 256 * 1024;
    float* wih_t_l0f = whh_t_l1b + 256 * 1024;  // [48][1024]
    float* wih_t_l0b = wih_t_l0f + 48 * 1024;
    float* wih_t_l1f = wih_t_l0b + 48 * 1024;   // [512][1024]
    float* wih_t_l1b = wih_t_l1f + 512 * 1024;

    float* state = ws + WT_FLOATS;
    float* h_l0 = state;                        // [2 parity][2 dir][B][H]
    float* h_l1 = h_l0 + 4 * BH;
    float* c_l0 = h_l1 + 4 * BH;                // [2 dir][B][H]
    float* c_l1 = c_l0 + 2 * BH;
    int*   flags = (int*)(state + STATE_FLOATS);
    void*  O0   = (void*)(state + STATE_FLOATS + FLAG_INTS);

    // ws_size is invariant across calls -> deterministic branch.
    const size_t base_bytes = (WT_FLOATS + STATE_FLOATS + FLAG_INTS) * sizeof(float);
    const bool o0_f32 = ws_size >= base_bytes + O0_ELEMS * sizeof(float);

    // zero h/c state AND sync flags (ws is poisoned 0xAA before every call)
    zero_f<<<(int)((STATE_FLOATS + FLAG_INTS + 255) / 256), 256, 0, stream>>>(
        state, (int)(STATE_FLOATS + FLAG_INTS));

    // weight transposes (per call; cheap, graph-captured)
    transpose_w<<<256 * 1024 / 256, 256, 0, stream>>>(w_hh_l0f, whh_t_l0f, 256);
    transpose_w<<<256 * 1024 / 256, 256, 0, stream>>>(w_hh_l0b, whh_t_l0b, 256);
    transpose_w<<<256 * 1024 / 256, 256, 0, stream>>>(w_hh_l1f, whh_t_l1f, 256);
    transpose_w<<<256 * 1024 / 256, 256, 0, stream>>>(w_hh_l1b, whh_t_l1b, 256);
    transpose_w<<<48 * 1024 / 256, 256, 0, stream>>>(w_ih_l0f, wih_t_l0f, 48);
    transpose_w<<<48 * 1024 / 256, 256, 0, stream>>>(w_ih_l0b, wih_t_l0b, 48);
    transpose_w<<<512 * 1024 / 256, 256, 0, stream>>>(w_ih_l1f, wih_t_l1f, 512);
    transpose_w<<<512 * 1024 / 256, 256, 0, stream>>>(w_ih_l1b, wih_t_l1b, 512);

    if (o0_f32) {
        lstm_persist<float><<<256, NT, 0, stream>>>(
            x,
            wih_t_l0f, wih_t_l0b, whh_t_l0f, whh_t_l0b,
            b_ih_l0f, b_hh_l0f, b_ih_l0b, b_hh_l0b,
            wih_t_l1f, wih_t_l1b, whh_t_l1f, whh_t_l1b,
            b_ih_l1f, b_hh_l1f, b_ih_l1b, b_hh_l1b,
            h_l0, h_l1, c_l0, c_l1,
            (float*)O0, lengths, flags);
    } else {
        lstm_persist<unsigned short><<<256, NT, 0, stream>>>(
            x,
            wih_t_l0f, wih_t_l0b, whh_t_l0f, whh_t_l0b,
            b_ih_l0f, b_hh_l0f, b_ih_l0b, b_hh_l0b,
            wih_t_l1f, wih_t_l1b, whh_t_l1f, whh_t_l1b,
            b_ih_l1f, b_hh_l1f, b_ih_l1b, b_hh_l1b,
            h_l0, h_l1, c_l0, c_l1,
            (unsigned short*)O0, lengths, flags);
    }
    // FC head: T even -> final h lives at parity 0
    fc_head<<<B, 256, 0, stream>>>(h_l1, fc1w, fc1b, fc2w, fc2b, (float*)d_out);
}

// Round 7
// 255983.667 us; speedup vs baseline: 1.7049x; 1.7049x over previous
//
#include <hip/hip_runtime.h>

namespace {

constexpr int B = 128;
constexpr int T = 1024;
constexpr int DIN = 48;
constexpr int H = 256;
constexpr int G = 4 * H;          // 1024 gate rows per direction
constexpr int NT = 512;           // threads per block: 16 k-slices x 32 row-quads

constexpr size_t BH           = (size_t)B * H;                       // 32768
constexpr size_t WT_FLOATS    = 4 * 256 * 1024 + 2 * 48 * 1024 + 2 * 512 * 1024; // 2,195,456
constexpr size_t STATE_FLOATS = 12 * BH;                             // 393,216
constexpr size_t FLAG_INTS    = 8192;                                // 32 grp x 8 members x 16 + barrier
constexpr size_t O0_ELEMS     = (size_t)B * T * 512;                 // 67,108,864

// Keep loaded values pinned in VGPRs: the asm may "modify" them, so the
// compiler can neither rematerialize the load (r6 failure: 1.22 TB refetch)
// nor fold it away. Zero runtime cost.
#define KEEP4(v) asm volatile("" : "+v"((v).x), "+v"((v).y), "+v"((v).z), "+v"((v).w))

__device__ __forceinline__ float sigmoidf_(float x) {
    float z = __expf(-fabsf(x));
    float s = 1.0f / (1.0f + z);
    return x >= 0.0f ? s : 1.0f - s;
}
__device__ __forceinline__ float tanhf_(float x) {
    float z = __expf(-2.0f * fabsf(x));
    float tp = (1.0f - z) / (1.0f + z);
    return x >= 0.0f ? tp : -tp;
}
__device__ __forceinline__ float bf2f(unsigned short s) {
    union { unsigned int u; float f; } v; v.u = ((unsigned int)s) << 16; return v.f;
}
__device__ __forceinline__ unsigned short f2bf(float f) {
    union { float f; unsigned int u; } v; v.f = f;
    unsigned int u = v.u;
    return (unsigned short)((u + 0x7FFFu + ((u >> 16) & 1u)) >> 16);  // RNE
}
__device__ __forceinline__ float fcomp(float4 v, int j) {
    return (j == 0) ? v.x : (j == 1) ? v.y : (j == 2) ? v.z : v.w;
}

__global__ void zero_f(float* __restrict__ p, int n) {
    int i = blockIdx.x * blockDim.x + threadIdx.x;
    if (i < n) p[i] = 0.0f;
}

// dst[k][r] = src[r][k], src is [1024][K]; output-coalesced
__global__ void transpose_w(const float* __restrict__ src, float* __restrict__ dst, int K) {
    int idx = blockIdx.x * blockDim.x + threadIdx.x;
    if (idx >= K * 1024) return;
    int r = idx & 1023;
    int k = idx >> 10;
    dst[idx] = src[r * K + k];
}

// Persistent, weight-stationary LSTM v3.
// 256 blocks x 512 threads, 1 block/CU (8 waves, 2/SIMD).
// __launch_bounds__(512,1): HIP arg2 = min BLOCKS/CU (CUDA semantics — r6
// measured: arg2=2 -> VGPR cap 128). 1 block/CU -> cap 256 >= demand ~238.
// Thread = (ks 0..15, rq 0..31). Register weights: L0 = 19 f4, L1 = 48 f4,
// laundered via KEEP4 so they stay in VGPRs (no remat, no refetch).
// Batch-split into 2 passes of 4 so acc is 16 regs, pass-scoped.
// Sync: per-member flag slots (store-only publish, poll 8), one grid barrier
// between layers. h/O0 coherence identical to the passing round-4/5/6 kernels.
template<typename OT>
__global__ __launch_bounds__(NT, 1)
void lstm_persist(const float* __restrict__ x,
    const float* __restrict__ wih0f, const float* __restrict__ wih0b,
    const float* __restrict__ whh0f, const float* __restrict__ whh0b,
    const float* __restrict__ bih0f, const float* __restrict__ bhh0f,
    const float* __restrict__ bih0b, const float* __restrict__ bhh0b,
    const float* __restrict__ wih1f, const float* __restrict__ wih1b,
    const float* __restrict__ whh1f, const float* __restrict__ whh1b,
    const float* __restrict__ bih1f, const float* __restrict__ bhh1f,
    const float* __restrict__ bih1b, const float* __restrict__ bhh1b,
    float* __restrict__ h_l0, float* __restrict__ h_l1,
    float* __restrict__ c_l0, float* __restrict__ c_l1,
    OT* __restrict__ O0, const int* __restrict__ lengths, int* __restrict__ flags)
{
    const int bx  = blockIdx.x;
    const int d   = bx >> 7;                 // 0 fwd, 1 bwd
    const int rem = bx & 127;
    const int b0  = (rem >> 3) * 8;
    const int c0  = (rem & 7) * 32;
    const int tid = threadIdx.x;
    const int ks  = tid & 15;                // 16 k-slices
    const int rq  = tid >> 4;                // 32 row-quads

    const int grp = d * 16 + (rem >> 3);     // sync group (dir, batch-tile): 8 members
    int* grpflags = flags + grp * 8 * 16;
    int* myflag   = grpflags + (rem & 7) * 16;

    const int gate  = rq >> 3;               // gate-major local rows
    const int chl4  = (rq & 7) << 2;
    const int grow0 = gate * 256 + c0 + chl4;    // global gate-row of acc[0] (f4-aligned)

    // gate-math mapping (first 256 threads active)
    const int gm_chl = tid & 31;
    const int gm_b   = (tid >> 5) & 7;       // &7: avoid OOB lengths read for tid>=256
    const int gm_gch = c0 + gm_chl;
    const int my_len = lengths[b0 + gm_b];

    // LDS layouts chosen for conflict-free 16-lane reads:
    //  x4: [b][kk2(8)][ks(16)] stride_b=132 -> read addrs consecutive in ks
    //  h4: [b][kk2(4)][ks(16)] stride_b=68
    __shared__ float  lds_x0[8 * 52];
    __shared__ float4 lds_x4[8 * 132];
    __shared__ float4 lds_h4[8 * 68];
    __shared__ float  lds_g[128 * 9];

    // ======================= phase 0: layer 0 =======================
    {
        const float* wih_t = d ? wih0b : wih0f;  // [48][1024]
        const float* whh_t = d ? whh0b : whh0f;  // [256][1024]
        const float* bih   = d ? bih0b : bih0f;
        const float* bhh   = d ? bhh0b : bhh0f;
        float* crow = c_l0 + d * (B * H);
        const float gm_bi[4] = { bih[0*256+gm_gch] + bhh[0*256+gm_gch],
                                 bih[1*256+gm_gch] + bhh[1*256+gm_gch],
                                 bih[2*256+gm_gch] + bhh[2*256+gm_gch],
                                 bih[3*256+gm_gch] + bhh[3*256+gm_gch] };

        // ---- weights -> VGPRs (once): 3 + 16 float4 ----
        float4 w0x[3], w0h[16];
        #pragma unroll
        for (int kk = 0; kk < 3; kk++)
            w0x[kk] = *(const float4*)(wih_t + (ks * 3 + kk) * G + grow0);
        #pragma unroll
        for (int kk = 0; kk < 16; kk++)
            w0h[kk] = *(const float4*)(whh_t + (ks * 16 + kk) * G + grow0);
        #pragma unroll
        for (int kk = 0; kk < 3; kk++) KEEP4(w0x[kk]);
        #pragma unroll
        for (int kk = 0; kk < 16; kk++) KEEP4(w0h[kk]);

        #pragma unroll 1
        for (int s = 0; s < T; ++s) {
            const int t = d ? (T - 1 - s) : s;
            const float* hrow_in  = h_l0 + ((size_t)((s & 1) * 2 + d)) * (B * H);
            float*       hrow_out = h_l0 + ((size_t)(((s & 1) ^ 1) * 2 + d)) * (B * H);

            // ---- stage x tile (8 x 48 scalars) ----
            if (tid < 384) {
                int b = tid / 48, k = tid - b * 48;
                lds_x0[b * 52 + k] = x[((size_t)(b0 + b) * T + t) * DIN + k];
            }
            __syncthreads();

            float acc[4][4];
            #pragma unroll
            for (int i = 0; i < 4; i++)
                #pragma unroll
                for (int bl = 0; bl < 4; bl++) acc[i][bl] = 0.0f;

            // ---- pass0 x-part (batches 0..3) BEFORE peer-wait ----
            #pragma unroll
            for (int kk = 0; kk < 3; kk++) {
                float4 w4 = w0x[kk];
                #pragma unroll
                for (int bl = 0; bl < 4; bl++) {
                    float xs = lds_x0[bl * 52 + ks * 3 + kk];
                    acc[0][bl] = fmaf(w4.x, xs, acc[0][bl]);
                    acc[1][bl] = fmaf(w4.y, xs, acc[1][bl]);
                    acc[2][bl] = fmaf(w4.z, xs, acc[2][bl]);
                    acc[3][bl] = fmaf(w4.w, xs, acc[3][bl]);
                }
            }

            // ---- wait: all 8 peers published step s-1 ----
            if (tid == 0) {
                for (;;) {
                    bool ready = true;
                    #pragma unroll
                    for (int m = 0; m < 8; m++)
                        ready &= (__hip_atomic_load(&grpflags[m * 16], __ATOMIC_RELAXED, __HIP_MEMORY_SCOPE_AGENT) >= s);
                    if (ready) break;
                    __builtin_amdgcn_s_sleep(2);
                }
            }
            __syncthreads();

            // ---- stage h (agent loads) ----
            #pragma unroll 1
            for (int i = tid; i < 8 * 256; i += NT) {
                int b = i >> 8, k = i & 255;
                float v = __hip_atomic_load(hrow_in + (b0 + b) * H + k,
                                            __ATOMIC_RELAXED, __HIP_MEMORY_SCOPE_AGENT);
                ((float*)lds_h4)[(b * 68 + ((k >> 2) & 3) * 16 + (k >> 4)) * 4 + (k & 3)] = v;
            }
            __syncthreads();

            // ---- pass0 h-part + reduce ----
            #pragma unroll
            for (int kk2 = 0; kk2 < 4; kk2++) {
                #pragma unroll
                for (int bl = 0; bl < 4; bl++) {
                    float4 hv = lds_h4[bl * 68 + kk2 * 16 + ks];
                    #pragma unroll
                    for (int j = 0; j < 4; j++) {
                        float4 w4 = w0h[kk2 * 4 + j];
                        float hs = fcomp(hv, j);
                        acc[0][bl] = fmaf(w4.x, hs, acc[0][bl]);
                        acc[1][bl] = fmaf(w4.y, hs, acc[1][bl]);
                        acc[2][bl] = fmaf(w4.z, hs, acc[2][bl]);
                        acc[3][bl] = fmaf(w4.w, hs, acc[3][bl]);
                    }
                }
            }
            #pragma unroll
            for (int i = 0; i < 4; i++)
                #pragma unroll
                for (int bl = 0; bl < 4; bl++) {
                    float v = acc[i][bl];
                    v += __shfl_xor(v, 1, 64);
                    v += __shfl_xor(v, 2, 64);
                    v += __shfl_xor(v, 4, 64);
                    v += __shfl_xor(v, 8, 64);
                    if (ks == 0) lds_g[(rq * 4 + i) * 9 + bl] = v;
                }

            // ---- pass1 (batches 4..7) ----
            #pragma unroll
            for (int i = 0; i < 4; i++)
                #pragma unroll
                for (int bl = 0; bl < 4; bl++) acc[i][bl] = 0.0f;
            #pragma unroll
            for (int kk = 0; kk < 3; kk++) {
                float4 w4 = w0x[kk];
                #pragma unroll
                for (int bl = 0; bl < 4; bl++) {
                    float xs = lds_x0[(4 + bl) * 52 + ks * 3 + kk];
                    acc[0][bl] = fmaf(w4.x, xs, acc[0][bl]);
                    acc[1][bl] = fmaf(w4.y, xs, acc[1][bl]);
                    acc[2][bl] = fmaf(w4.z, xs, acc[2][bl]);
                    acc[3][bl] = fmaf(w4.w, xs, acc[3][bl]);
                }
            }
            #pragma unroll
            for (int kk2 = 0; kk2 < 4; kk2++) {
                #pragma unroll
                for (int bl = 0; bl < 4; bl++) {
                    float4 hv = lds_h4[(4 + bl) * 68 + kk2 * 16 + ks];
                    #pragma unroll
                    for (int j = 0; j < 4; j++) {
                        float4 w4 = w0h[kk2 * 4 + j];
                        float hs = fcomp(hv, j);
                        acc[0][bl] = fmaf(w4.x, hs, acc[0][bl]);
                        acc[1][bl] = fmaf(w4.y, hs, acc[1][bl]);
                        acc[2][bl] = fmaf(w4.z, hs, acc[2][bl]);
                        acc[3][bl] = fmaf(w4.w, hs, acc[3][bl]);
                    }
                }
            }
            #pragma unroll
            for (int i = 0; i < 4; i++)
                #pragma unroll
                for (int bl = 0; bl < 4; bl++) {
                    float v = acc[i][bl];
                    v += __shfl_xor(v, 1, 64);
                    v += __shfl_xor(v, 2, 64);
                    v += __shfl_xor(v, 4, 64);
                    v += __shfl_xor(v, 8, 64);
                    if (ks == 0) lds_g[(rq * 4 + i) * 9 + 4 + bl] = v;
                }
            __syncthreads();

            // ---- gate math (first 256 threads) ----
            if (tid < 256) {
                float gi = lds_g[(0 * 32 + gm_chl) * 9 + gm_b] + gm_bi[0];
                float gf = lds_g[(1 * 32 + gm_chl) * 9 + gm_b] + gm_bi[1];
                float gg = lds_g[(2 * 32 + gm_chl) * 9 + gm_b] + gm_bi[2];
                float go = lds_g[(3 * 32 + gm_chl) * 9 + gm_b] + gm_bi[3];
                float iv = sigmoidf_(gi);
                float fv = sigmoidf_(gf);
                float gv = tanhf_(gg);
                float ov = sigmoidf_(go);
                const int sidx = (b0 + gm_b) * H + gm_gch;
                float c_old = crow[sidx];
                float h_old = ((float*)lds_h4)[(gm_b * 68 + ((gm_gch >> 2) & 3) * 16 + (gm_gch >> 4)) * 4 + (gm_gch & 3)];
                float c_new = fv * c_old + iv * gv;
                float h_new = ov * tanhf_(c_new);
                bool valid = t < my_len;
                if (valid) crow[sidx] = c_new;
                __hip_atomic_store(hrow_out + sidx, valid ? h_new : h_old,
                                   __ATOMIC_RELAXED, __HIP_MEMORY_SCOPE_AGENT);
                float hv_o = valid ? h_new : 0.0f;
                size_t oidx = ((size_t)(b0 + gm_b) * T + t) * 512 + d * 256 + gm_gch;
                if constexpr (sizeof(OT) == 4)
                    __hip_atomic_store(O0 + oidx, hv_o, __ATOMIC_RELAXED, __HIP_MEMORY_SCOPE_AGENT);
                else
                    __hip_atomic_store(O0 + oidx, f2bf(hv_o), __ATOMIC_RELAXED, __HIP_MEMORY_SCOPE_AGENT);
            }
            __syncthreads();   // drain h/O0 stores before publish
            if (tid == 0)
                __hip_atomic_store(myflag, s + 1, __ATOMIC_RELAXED, __HIP_MEMORY_SCOPE_AGENT);
        }
    }

    // ======================= grid-wide phase barrier =======================
    __syncthreads();
    if (tid == 0) {
        __threadfence();
        __hip_atomic_fetch_add(&flags[32 * 8 * 16], 1, __ATOMIC_ACQ_REL, __HIP_MEMORY_SCOPE_AGENT);
        while (__hip_atomic_load(&flags[32 * 8 * 16], __ATOMIC_ACQUIRE, __HIP_MEMORY_SCOPE_AGENT) < 256)
            __builtin_amdgcn_s_sleep(2);
        __threadfence();
    }
    __syncthreads();

    // ======================= phase 1: layer 1 =======================
    {
        const float* wih_t = d ? wih1b : wih1f;  // [512][1024]
        const float* whh_t = d ? whh1b : whh1f;  // [256][1024]
        const float* bih   = d ? bih1b : bih1f;
        const float* bhh   = d ? bhh1b : bhh1f;
        float* crow = c_l1 + d * (B * H);
        const float gm_bi[4] = { bih[0*256+gm_gch] + bhh[0*256+gm_gch],
                                 bih[1*256+gm_gch] + bhh[1*256+gm_gch],
                                 bih[2*256+gm_gch] + bhh[2*256+gm_gch],
                                 bih[3*256+gm_gch] + bhh[3*256+gm_gch] };

        // ---- weights -> VGPRs (once): 32 + 16 float4 = 192 VGPRs ----
        float4 w1x[32], w1h[16];
        #pragma unroll
        for (int kk = 0; kk < 32; kk++)
            w1x[kk] = *(const float4*)(wih_t + (ks * 32 + kk) * G + grow0);
        #pragma unroll
        for (int kk = 0; kk < 16; kk++)
            w1h[kk] = *(const float4*)(whh_t + (ks * 16 + kk) * G + grow0);
        #pragma unroll
        for (int kk = 0; kk < 32; kk++) KEEP4(w1x[kk]);
        #pragma unroll
        for (int kk = 0; kk < 16; kk++) KEEP4(w1h[kk]);

        #pragma unroll 1
        for (int s = 0; s < T; ++s) {
            const int t = d ? (T - 1 - s) : s;
            const float* hrow_in  = h_l1 + ((size_t)((s & 1) * 2 + d)) * (B * H);
            float*       hrow_out = h_l1 + ((size_t)(((s & 1) ^ 1) * 2 + d)) * (B * H);

            // ---- stage x tile from O0 (1024 f4, 2/thread) ----
            #pragma unroll
            for (int ii = 0; ii < 2; ii++) {
                int i = tid + ii * NT;
                int b = i >> 7, kq = i & 127;
                float4 v;
                if constexpr (sizeof(OT) == 4) {
                    v = *(const float4*)((const float*)O0 + ((size_t)(b0 + b) * T + t) * 512 + kq * 4);
                } else {
                    ushort4 uv = *(const ushort4*)((const unsigned short*)O0 + ((size_t)(b0 + b) * T + t) * 512 + kq * 4);
                    v = make_float4(bf2f(uv.x), bf2f(uv.y), bf2f(uv.z), bf2f(uv.w));
                }
                lds_x4[b * 132 + (kq & 7) * 16 + (kq >> 3)] = v;
            }
            __syncthreads();

            float acc[4][4];
            #pragma unroll
            for (int i = 0; i < 4; i++)
                #pragma unroll
                for (int bl = 0; bl < 4; bl++) acc[i][bl] = 0.0f;

            // ---- pass0 x-part (batches 0..3) BEFORE peer-wait ----
            #pragma unroll
            for (int kk2 = 0; kk2 < 8; kk2++) {
                #pragma unroll
                for (int bl = 0; bl < 4; bl++) {
                    float4 xv = lds_x4[bl * 132 + kk2 * 16 + ks];
                    #pragma unroll
                    for (int j = 0; j < 4; j++) {
                        float4 w4 = w1x[kk2 * 4 + j];
                        float xs = fcomp(xv, j);
                        acc[0][bl] = fmaf(w4.x, xs, acc[0][bl]);
                        acc[1][bl] = fmaf(w4.y, xs, acc[1][bl]);
                        acc[2][bl] = fmaf(w4.z, xs, acc[2][bl]);
                        acc[3][bl] = fmaf(w4.w, xs, acc[3][bl]);
                    }
                }
            }

            // ---- wait: all 8 peers >= T + s ----
            if (tid == 0) {
                const int target = T + s;
                for (;;) {
                    bool ready = true;
                    #pragma unroll
                    for (int m = 0; m < 8; m++)
                        ready &= (__hip_atomic_load(&grpflags[m * 16], __ATOMIC_RELAXED, __HIP_MEMORY_SCOPE_AGENT) >= target);
                    if (ready) break;
                    __builtin_amdgcn_s_sleep(2);
                }
            }
            __syncthreads();

            // ---- stage h ----
            #pragma unroll 1
            for (int i = tid; i < 8 * 256; i += NT) {
                int b = i >> 8, k = i & 255;
                float v = __hip_atomic_load(hrow_in + (b0 + b) * H + k,
                                            __ATOMIC_RELAXED, __HIP_MEMORY_SCOPE_AGENT);
                ((float*)lds_h4)[(b * 68 + ((k >> 2) & 3) * 16 + (k >> 4)) * 4 + (k & 3)] = v;
            }
            __syncthreads();

            // ---- pass0 h-part + reduce ----
            #pragma unroll
            for (int kk2 = 0; kk2 < 4; kk2++) {
                #pragma unroll
                for (int bl = 0; bl < 4; bl++) {
                    float4 hv = lds_h4[bl * 68 + kk2 * 16 + ks];
                    #pragma unroll
                    for (int j = 0; j < 4; j++) {
                        float4 w4 = w1h[kk2 * 4 + j];
                        float hs = fcomp(hv, j);
                        acc[0][bl] = fmaf(w4.x, hs, acc[0][bl]);
                        acc[1][bl] = fmaf(w4.y, hs, acc[1][bl]);
                        acc[2][bl] = fmaf(w4.z, hs, acc[2][bl]);
                        acc[3][bl] = fmaf(w4.w, hs, acc[3][bl]);
                    }
                }
            }
            #pragma unroll
            for (int i = 0; i < 4; i++)
                #pragma unroll
                for (int bl = 0; bl < 4; bl++) {
                    float v = acc[i][bl];
                    v += __shfl_xor(v, 1, 64);
                    v += __shfl_xor(v, 2, 64);
                    v += __shfl_xor(v, 4, 64);
                    v += __shfl_xor(v, 8, 64);
                    if (ks == 0) lds_g[(rq * 4 + i) * 9 + bl] = v;
                }

            // ---- pass1 (batches 4..7) ----
            #pragma unroll
            for (int i = 0; i < 4; i++)
                #pragma unroll
                for (int bl = 0; bl < 4; bl++) acc[i][bl] = 0.0f;
            #pragma unroll
            for (int kk2 = 0; kk2 < 8; kk2++) {
                #pragma unroll
                for (int bl = 0; bl < 4; bl++) {
                    float4 xv = lds_x4[(4 + bl) * 132 + kk2 * 16 + ks];
                    #pragma unroll
                    for (int j = 0; j < 4; j++) {
                        float4 w4 = w1x[kk2 * 4 + j];
                        float xs = fcomp(xv, j);
                        acc[0][bl] = fmaf(w4.x, xs, acc[0][bl]);
                        acc[1][bl] = fmaf(w4.y, xs, acc[1][bl]);
                        acc[2][bl] = fmaf(w4.z, xs, acc[2][bl]);
                        acc[3][bl] = fmaf(w4.w, xs, acc[3][bl]);
                    }
                }
            }
            #pragma unroll
            for (int kk2 = 0; kk2 < 4; kk2++) {
                #pragma unroll
                for (int bl = 0; bl < 4; bl++) {
                    float4 hv = lds_h4[(4 + bl) * 68 + kk2 * 16 + ks];
                    #pragma unroll
                    for (int j = 0; j < 4; j++) {
                        float4 w4 = w1h[kk2 * 4 + j];
                        float hs = fcomp(hv, j);
                        acc[0][bl] = fmaf(w4.x, hs, acc[0][bl]);
                        acc[1][bl] = fmaf(w4.y, hs, acc[1][bl]);
                        acc[2][bl] = fmaf(w4.z, hs, acc[2][bl]);
                        acc[3][bl] = fmaf(w4.w, hs, acc[3][bl]);
                    }
                }
            }
            #pragma unroll
            for (int i = 0; i < 4; i++)
                #pragma unroll
                for (int bl = 0; bl < 4; bl++) {
                    float v = acc[i][bl];
                    v += __shfl_xor(v, 1, 64);
                    v += __shfl_xor(v, 2, 64);
                    v += __shfl_xor(v, 4, 64);
                    v += __shfl_xor(v, 8, 64);
                    if (ks == 0) lds_g[(rq * 4 + i) * 9 + 4 + bl] = v;
                }
            __syncthreads();

            // ---- gate math ----
            if (tid < 256) {
                float gi = lds_g[(0 * 32 + gm_chl) * 9 + gm_b] + gm_bi[0];
                float gf = lds_g[(1 * 32 + gm_chl) * 9 + gm_b] + gm_bi[1];
                float gg = lds_g[(2 * 32 + gm_chl) * 9 + gm_b] + gm_bi[2];
                float go = lds_g[(3 * 32 + gm_chl) * 9 + gm_b] + gm_bi[3];
                float iv = sigmoidf_(gi);
                float fv = sigmoidf_(gf);
                float gv = tanhf_(gg);
                float ov = sigmoidf_(go);
                const int sidx = (b0 + gm_b) * H + gm_gch;
                float c_old = crow[sidx];
                float h_old = ((float*)lds_h4)[(gm_b * 68 + ((gm_gch >> 2) & 3) * 16 + (gm_gch >> 4)) * 4 + (gm_gch & 3)];
                float c_new = fv * c_old + iv * gv;
                float h_new = ov * tanhf_(c_new);
                bool valid = t < my_len;
                if (valid) crow[sidx] = c_new;
                __hip_atomic_store(hrow_out + sidx, valid ? h_new : h_old,
                                   __ATOMIC_RELAXED, __HIP_MEMORY_SCOPE_AGENT);
            }
            __syncthreads();
            if (tid == 0)
                __hip_atomic_store(myflag, T + s + 1, __ATOMIC_RELAXED, __HIP_MEMORY_SCOPE_AGENT);
        }
    }
}

__global__ __launch_bounds__(256)
void fc_head(const float* __restrict__ h1,   // [2][B][H] final layer-1 h (parity 0)
             const float* __restrict__ fc1w, const float* __restrict__ fc1b,
             const float* __restrict__ fc2w, const float* __restrict__ fc2b,
             float* __restrict__ out)
{
    int b = blockIdx.x;
    int tid = threadIdx.x;
    __shared__ float hid[512];
    __shared__ float red[4];
    hid[tid]       = h1[b * H + tid];
    hid[256 + tid] = h1[(size_t)B * H + b * H + tid];
    __syncthreads();
    float a = fc1b[tid];
    const float4* w4 = (const float4*)(fc1w + tid * 512);
    const float4* h4 = (const float4*)hid;
    #pragma unroll 4
    for (int k = 0; k < 128; k++) {
        float4 w = w4[k], h = h4[k];
        a = fmaf(w.x, h.x, a); a = fmaf(w.y, h.y, a);
        a = fmaf(w.z, h.z, a); a = fmaf(w.w, h.w, a);
    }
    float r = fmaxf(a, 0.0f);
    float v = r * fc2w[tid];
    #pragma unroll
    for (int off = 32; off > 0; off >>= 1) v += __shfl_down(v, off, 64);
    if ((tid & 63) == 0) red[tid >> 6] = v;
    __syncthreads();
    if (tid == 0) out[b] = red[0] + red[1] + red[2] + red[3] + fc2b[0];
}

} // namespace

extern "C" void kernel_launch(void* const* d_in, const int* in_sizes, int n_in,
                              void* d_out, int out_size, void* d_ws, size_t ws_size,
                              hipStream_t stream)
{
    const float* x        = (const float*)d_in[0];
    const int*   lengths  = (const int*)d_in[1];
    const float* w_ih_l0f = (const float*)d_in[2];
    const float* w_hh_l0f = (const float*)d_in[3];
    const float* b_ih_l0f = (const float*)d_in[4];
    const float* b_hh_l0f = (const float*)d_in[5];
    const float* w_ih_l0b = (const float*)d_in[6];
    const float* w_hh_l0b = (const float*)d_in[7];
    const float* b_ih_l0b = (const float*)d_in[8];
    const float* b_hh_l0b = (const float*)d_in[9];
    const float* w_ih_l1f = (const float*)d_in[10];
    const float* w_hh_l1f = (const float*)d_in[11];
    const float* b_ih_l1f = (const float*)d_in[12];
    const float* b_hh_l1f = (const float*)d_in[13];
    const float* w_ih_l1b = (const float*)d_in[14];
    const float* w_hh_l1b = (const float*)d_in[15];
    const float* b_ih_l1b = (const float*)d_in[16];
    const float* b_hh_l1b = (const float*)d_in[17];
    const float* fc1w     = (const float*)d_in[18];
    const float* fc1b     = (const float*)d_in[19];
    const float* fc2w     = (const float*)d_in[20];
    const float* fc2b     = (const float*)d_in[21];

    float* ws = (float*)d_ws;

    // ---- workspace layout: [weights | state | flags | O0] ----
    float* whh_t_l0f = ws;
    float* whh_t_l0b = whh_t_l0f + 256 * 1024;
    float* whh_t_l1f = whh_t_l0b + 256 * 1024;
    float* whh_t_l1b = whh_t_l1f + 256 * 1024;
    float* wih_t_l0f = whh_t_l1b + 256 * 1024;  // [48][1024]
    float* wih_t_l0b = wih_t_l0f + 48 * 1024;
    float* wih_t_l1f = wih_t_l0b + 48 * 1024;   // [512][1024]
    float* wih_t_l1b = wih_t_l1f + 512 * 1024;

    float* state = ws + WT_FLOATS;
    float* h_l0 = state;                        // [2 parity][2 dir][B][H]
    float* h_l1 = h_l0 + 4 * BH;
    float* c_l0 = h_l1 + 4 * BH;                // [2 dir][B][H]
    float* c_l1 = c_l0 + 2 * BH;
    int*   flags = (int*)(state + STATE_FLOATS);
    void*  O0   = (void*)(state + STATE_FLOATS + FLAG_INTS);

    // ws_size is invariant across calls -> deterministic branch.
    const size_t base_bytes = (WT_FLOATS + STATE_FLOATS + FLAG_INTS) * sizeof(float);
    const bool o0_f32 = ws_size >= base_bytes + O0_ELEMS * sizeof(float);

    // zero h/c state AND sync flags (ws is poisoned 0xAA before every call)
    zero_f<<<(int)((STATE_FLOATS + FLAG_INTS + 255) / 256), 256, 0, stream>>>(
        state, (int)(STATE_FLOATS + FLAG_INTS));

    // weight transposes (per call; cheap, graph-captured)
    transpose_w<<<256 * 1024 / 256, 256, 0, stream>>>(w_hh_l0f, whh_t_l0f, 256);
    transpose_w<<<256 * 1024 / 256, 256, 0, stream>>>(w_hh_l0b, whh_t_l0b, 256);
    transpose_w<<<256 * 1024 / 256, 256, 0, stream>>>(w_hh_l1f, whh_t_l1f, 256);
    transpose_w<<<256 * 1024 / 256, 256, 0, stream>>>(w_hh_l1b, whh_t_l1b, 256);
    transpose_w<<<48 * 1024 / 256, 256, 0, stream>>>(w_ih_l0f, wih_t_l0f, 48);
    transpose_w<<<48 * 1024 / 256, 256, 0, stream>>>(w_ih_l0b, wih_t_l0b, 48);
    transpose_w<<<512 * 1024 / 256, 256, 0, stream>>>(w_ih_l1f, wih_t_l1f, 512);
    transpose_w<<<512 * 1024 / 256, 256, 0, stream>>>(w_ih_l1b, wih_t_l1b, 512);

    if (o0_f32) {
        lstm_persist<float><<<256, NT, 0, stream>>>(
            x,
            wih_t_l0f, wih_t_l0b, whh_t_l0f, whh_t_l0b,
            b_ih_l0f, b_hh_l0f, b_ih_l0b, b_hh_l0b,
            wih_t_l1f, wih_t_l1b, whh_t_l1f, whh_t_l1b,
            b_ih_l1f, b_hh_l1f, b_ih_l1b, b_hh_l1b,
            h_l0, h_l1, c_l0, c_l1,
            (float*)O0, lengths, flags);
    } else {
        lstm_persist<unsigned short><<<256, NT, 0, stream>>>(
            x,
            wih_t_l0f, wih_t_l0b, whh_t_l0f, whh_t_l0b,
            b_ih_l0f, b_hh_l0f, b_ih_l0b, b_hh_l0b,
            wih_t_l1f, wih_t_l1b, whh_t_l1f, whh_t_l1b,
            b_ih_l1f, b_hh_l1f, b_ih_l1b, b_hh_l1b,
            h_l0, h_l1, c_l0, c_l1,
            (unsigned short*)O0, lengths, flags);
    }
    // FC head: T even -> final h lives at parity 0
    fc_head<<<B, 256, 0, stream>>>(h_l1, fc1w, fc1b, fc2w, fc2b, (float*)d_out);
}

// Round 8
// 65480.365 us; speedup vs baseline: 6.6649x; 3.9093x over previous
//
#include <hip/hip_runtime.h>

namespace {

constexpr int B = 128;
constexpr int T = 1024;
constexpr int DIN = 48;
constexpr int H = 256;
constexpr int NT = 512;           // 16 k-slices x 32 row-quads

constexpr size_t BH           = (size_t)B * H;                       // 32768
constexpr size_t STATE_FLOATS = 12 * BH;                             // 393,216
constexpr size_t FLAG_INTS    = 8192;
constexpr size_t O0_ELEMS     = (size_t)B * T * 512;                 // 67,108,864

__device__ __forceinline__ float sigmoidf_(float x) {
    float z = __expf(-fabsf(x));
    float s = 1.0f / (1.0f + z);
    return x >= 0.0f ? s : 1.0f - s;
}
__device__ __forceinline__ float tanhf_(float x) {
    float z = __expf(-2.0f * fabsf(x));
    float tp = (1.0f - z) / (1.0f + z);
    return x >= 0.0f ? tp : -tp;
}
__device__ __forceinline__ float bf2f(unsigned short s) {
    union { unsigned int u; float f; } v; v.u = ((unsigned int)s) << 16; return v.f;
}
__device__ __forceinline__ unsigned short f2bf(float f) {
    union { float f; unsigned int u; } v; v.f = f;
    unsigned int u = v.u;
    return (unsigned short)((u + 0x7FFFu + ((u >> 16) & 1u)) >> 16);  // RNE
}

__global__ void zero_f(float* __restrict__ p, int n) {
    int i = blockIdx.x * blockDim.x + threadIdx.x;
    if (i < n) p[i] = 0.0f;
}

// One recurrence step for one block (dir d, 8-batch tile b0, 32-channel tile c0).
// Weights read ROW-MAJOR directly from d_in ([1024][INP] / [1024][256]) —
// K-contiguous float4 per gate-row. Same FMA accumulation order as the
// passing r4 kernel (k ascending per acc) -> bit-identical partial sums.
// XF4 = float4-per-k-slice for the x part; KSX = active k-slices for x.
template<int INP, int XF4, int XSL, int XPB, int KSX, bool WRITE_OUT, typename XT, typename OT>
__device__ __forceinline__ void step_body(
    int t, int dsel, int b0, int c0, int grow0, int ks, int rq,
    const XT* __restrict__ xin, int xstride,
    const float* __restrict__ wih, const float* __restrict__ whh,   // row-major
    const float* __restrict__ bih,  const float* __restrict__ bhh,
    const float* __restrict__ hrow_in, float* __restrict__ hrow_out,
    float* __restrict__ crow, OT* __restrict__ oout,
    int my_len,
    float4* lds_x4, float4* lds_h4, float* lds_g,
    int* grpflags, int* myflag, int wait_target, int publish_val)
{
    const int tid = threadIdx.x;

    // ---- stage x tile (issued BEFORE the wait: overlaps publish latency) ----
    {
        const int nchunk = INP / 4;
        for (int i = tid; i < 8 * nchunk; i += NT) {
            int b, k4;
            if constexpr (INP == 48) { b = i / 12; k4 = i - b * 12; }
            else                     { b = i >> 7; k4 = i & 127; }
            const XT* src = xin + ((size_t)(b0 + b) * T + t) * xstride + k4 * 4;
            float4 v;
            if constexpr (sizeof(XT) == 4) {
                v = *(const float4*)src;
            } else {
                ushort4 uv = *(const ushort4*)src;
                v = make_float4(bf2f(uv.x), bf2f(uv.y), bf2f(uv.z), bf2f(uv.w));
            }
            int slot;
            if constexpr (INP == 48) slot = b * XPB + k4 * XSL;                      // XF4=1: k4==ks
            else                     slot = b * XPB + (k4 >> 3) * XSL + (k4 & 7);    // XF4=8
            lds_x4[slot] = v;
        }
    }

    // ---- wait: all 8 group peers have published the previous step ----
    if (wait_target > 0) {
        if (tid == 0) {
            for (;;) {
                bool ready = true;
                #pragma unroll
                for (int m = 0; m < 8; m++)
                    ready &= (__hip_atomic_load(&grpflags[m * 16], __ATOMIC_RELAXED, __HIP_MEMORY_SCOPE_AGENT) >= wait_target);
                if (ready) break;
                __builtin_amdgcn_s_sleep(2);
            }
        }
        __syncthreads();
    } else {
        __syncthreads();   // x staged
    }

    // ---- stage h tile (agent-scope loads -> coherent point) ----
    #pragma unroll 1
    for (int i = tid; i < 8 * 256; i += NT) {
        int b = i >> 8, k = i & 255;
        float v = __hip_atomic_load(hrow_in + (b0 + b) * H + k,
                                    __ATOMIC_RELAXED, __HIP_MEMORY_SCOPE_AGENT);
        ((float*)lds_h4)[(b * 80 + (k >> 4) * 5 + ((k >> 2) & 3)) * 4 + (k & 3)] = v;
    }
    __syncthreads();

    float acc[4][8];
    #pragma unroll
    for (int i = 0; i < 4; i++)
        #pragma unroll
        for (int b = 0; b < 8; b++) acc[i][b] = 0.0f;

    // ---- x part: row-major weights, K-contiguous f4 per gate-row ----
    if (ks < KSX) {
        #pragma unroll
        for (int kk = 0; kk < XF4; kk++) {
            float4 xv[8];
            #pragma unroll
            for (int b = 0; b < 8; b++) xv[b] = lds_x4[b * XPB + ks * XSL + kk];
            const int kb = (ks * XF4 + kk) * 4;
            #pragma unroll
            for (int i = 0; i < 4; i++) {
                float4 w4 = *(const float4*)(wih + (size_t)(grow0 + i) * INP + kb);
                #pragma unroll
                for (int b = 0; b < 8; b++) {
                    acc[i][b] = fmaf(w4.x, xv[b].x, acc[i][b]);
                    acc[i][b] = fmaf(w4.y, xv[b].y, acc[i][b]);
                    acc[i][b] = fmaf(w4.z, xv[b].z, acc[i][b]);
                    acc[i][b] = fmaf(w4.w, xv[b].w, acc[i][b]);
                }
            }
        }
    }

    // ---- h part: K=256, 4 f4 per k-slice ----
    #pragma unroll
    for (int kk = 0; kk < 4; kk++) {
        float4 hv[8];
        #pragma unroll
        for (int b = 0; b < 8; b++) hv[b] = lds_h4[b * 80 + ks * 5 + kk];
        const int kb = (ks * 4 + kk) * 4;
        #pragma unroll
        for (int i = 0; i < 4; i++) {
            float4 w4 = *(const float4*)(whh + (size_t)(grow0 + i) * 256 + kb);
            #pragma unroll
            for (int b = 0; b < 8; b++) {
                acc[i][b] = fmaf(w4.x, hv[b].x, acc[i][b]);
                acc[i][b] = fmaf(w4.y, hv[b].y, acc[i][b]);
                acc[i][b] = fmaf(w4.z, hv[b].z, acc[i][b]);
                acc[i][b] = fmaf(w4.w, hv[b].w, acc[i][b]);
            }
        }
    }

    // ---- reduce over the 16 k-slices (lane bits 0..3) ----
    #pragma unroll
    for (int i = 0; i < 4; i++)
        #pragma unroll
        for (int b = 0; b < 8; b++) {
            float v = acc[i][b];
            v += __shfl_xor(v, 1, 64);
            v += __shfl_xor(v, 2, 64);
            v += __shfl_xor(v, 4, 64);
            v += __shfl_xor(v, 8, 64);
            acc[i][b] = v;
        }
    if (ks == 0) {
        #pragma unroll
        for (int i = 0; i < 4; i++)
            #pragma unroll
            for (int b = 0; b < 8; b++)
                lds_g[(rq * 4 + i) * 9 + b] = acc[i][b];
    }
    __syncthreads();

    // ---- elementwise gate math: 256 (channel, batch) pairs ----
    if (tid < 256) {
        const int chl = tid & 31;
        const int b   = tid >> 5;
        const int gch = c0 + chl;
        float gi = lds_g[(0 * 32 + chl) * 9 + b] + bih[0 * 256 + gch] + bhh[0 * 256 + gch];
        float gf = lds_g[(1 * 32 + chl) * 9 + b] + bih[1 * 256 + gch] + bhh[1 * 256 + gch];
        float gg = lds_g[(2 * 32 + chl) * 9 + b] + bih[2 * 256 + gch] + bhh[2 * 256 + gch];
        float go = lds_g[(3 * 32 + chl) * 9 + b] + bih[3 * 256 + gch] + bhh[3 * 256 + gch];
        float iv = sigmoidf_(gi);
        float fv = sigmoidf_(gf);
        float gv = tanhf_(gg);
        float ov = sigmoidf_(go);
        const int sidx = (b0 + b) * H + gch;
        float c_old = crow[sidx];
        float h_old = ((float*)lds_h4)[(b * 80 + (gch >> 4) * 5 + ((gch >> 2) & 3)) * 4 + (gch & 3)];
        float c_new = fv * c_old + iv * gv;
        float h_new = ov * tanhf_(c_new);
        bool valid = t < my_len;
        if (valid) crow[sidx] = c_new;
        __hip_atomic_store(hrow_out + sidx, valid ? h_new : h_old,
                           __ATOMIC_RELAXED, __HIP_MEMORY_SCOPE_AGENT);
        if constexpr (WRITE_OUT) {
            float hv_o = valid ? h_new : 0.0f;
            size_t oidx = ((size_t)(b0 + b) * T + t) * 512 + dsel * 256 + gch;
            if constexpr (sizeof(OT) == 4)
                __hip_atomic_store(oout + oidx, hv_o, __ATOMIC_RELAXED, __HIP_MEMORY_SCOPE_AGENT);
            else
                __hip_atomic_store(oout + oidx, f2bf(hv_o), __ATOMIC_RELAXED, __HIP_MEMORY_SCOPE_AGENT);
        }
    }
    __syncthreads();   // drain h/O0 stores before publish
    if (tid == 0)
        __hip_atomic_store(myflag, publish_val, __ATOMIC_RELAXED, __HIP_MEMORY_SCOPE_AGENT);
}

// Persistent kernel: whole 2x1024-step recurrence in one dispatch.
// 256 blocks x 512 threads. Weights stream from d_in (row-major, L2-cacheable).
// Sync: 32 groups x 8 per-member flag slots; one grid barrier between layers.
template<typename OT>
__global__ __launch_bounds__(NT)
void lstm_persist(const float* __restrict__ x,
    const float* __restrict__ wih0f, const float* __restrict__ wih0b,
    const float* __restrict__ whh0f, const float* __restrict__ whh0b,
    const float* __restrict__ bih0f, const float* __restrict__ bhh0f,
    const float* __restrict__ bih0b, const float* __restrict__ bhh0b,
    const float* __restrict__ wih1f, const float* __restrict__ wih1b,
    const float* __restrict__ whh1f, const float* __restrict__ whh1b,
    const float* __restrict__ bih1f, const float* __restrict__ bhh1f,
    const float* __restrict__ bih1b, const float* __restrict__ bhh1b,
    float* __restrict__ h_l0, float* __restrict__ h_l1,
    float* __restrict__ c_l0, float* __restrict__ c_l1,
    OT* __restrict__ O0, const int* __restrict__ lengths, int* __restrict__ flags)
{
    const int bx  = blockIdx.x;
    const int d   = bx >> 7;                 // 0 fwd, 1 bwd
    const int rem = bx & 127;
    const int b0  = (rem >> 3) * 8;
    const int c0  = (rem & 7) * 32;          // ctile = bx&7 -> per-XCD weight locality
    const int tid = threadIdx.x;
    const int ks  = tid & 15;
    const int rq  = tid >> 4;

    const int grp = d * 16 + (rem >> 3);
    int* grpflags = flags + grp * 8 * 16;
    int* myflag   = grpflags + (rem & 7) * 16;

    const int gate  = rq >> 3;
    const int chl4  = (rq & 7) << 2;
    const int grow0 = gate * 256 + c0 + chl4;

    const int my_len = lengths[b0 + ((tid >> 5) & 7)];

    __shared__ float4 lds_x4[8 * 144];
    __shared__ float4 lds_h4[8 * 80];
    __shared__ float  lds_g[128 * 9];

    // ================= phase 0: layer 0 =================
    {
        const float* wih = d ? wih0b : wih0f;   // [1024][48]
        const float* whh = d ? whh0b : whh0f;   // [1024][256]
        const float* bih = d ? bih0b : bih0f;
        const float* bhh = d ? bhh0b : bhh0f;
        float* crow = c_l0 + d * (B * H);
        #pragma unroll 1
        for (int s = 0; s < T; ++s) {
            const int t = d ? (T - 1 - s) : s;
            const float* hin = h_l0 + ((size_t)((s & 1) * 2 + d)) * (B * H);
            float*       hout= h_l0 + ((size_t)(((s & 1) ^ 1) * 2 + d)) * (B * H);
            step_body<48, 1, 3, 48, 12, true, float, OT>(
                t, d, b0, c0, grow0, ks, rq, x, DIN, wih, whh, bih, bhh,
                hin, hout, crow, O0, my_len, lds_x4, lds_h4, lds_g,
                grpflags, myflag, s, s + 1);
        }
    }

    // ================= grid-wide phase barrier =================
    __syncthreads();
    if (tid == 0) {
        __threadfence();
        __hip_atomic_fetch_add(&flags[32 * 8 * 16], 1, __ATOMIC_ACQ_REL, __HIP_MEMORY_SCOPE_AGENT);
        while (__hip_atomic_load(&flags[32 * 8 * 16], __ATOMIC_ACQUIRE, __HIP_MEMORY_SCOPE_AGENT) < 256)
            __builtin_amdgcn_s_sleep(2);
        __threadfence();
    }
    __syncthreads();

    // ================= phase 1: layer 1 =================
    {
        const float* wih = d ? wih1b : wih1f;   // [1024][512]
        const float* whh = d ? whh1b : whh1f;   // [1024][256]
        const float* bih = d ? bih1b : bih1f;
        const float* bhh = d ? bhh1b : bhh1f;
        float* crow = c_l1 + d * (B * H);
        #pragma unroll 1
        for (int s = 0; s < T; ++s) {
            const int t = d ? (T - 1 - s) : s;
            const float* hin = h_l1 + ((size_t)((s & 1) * 2 + d)) * (B * H);
            float*       hout= h_l1 + ((size_t)(((s & 1) ^ 1) * 2 + d)) * (B * H);
            step_body<512, 8, 9, 144, 16, false, OT, OT>(
                t, d, b0, c0, grow0, ks, rq, O0, 512, wih, whh, bih, bhh,
                hin, hout, crow, (OT*)nullptr, my_len, lds_x4, lds_h4, lds_g,
                grpflags, myflag, T + s, T + s + 1);
        }
    }
}

__global__ __launch_bounds__(256)
void fc_head(const float* __restrict__ h1,   // [2][B][H] final layer-1 h (parity 0)
             const float* __restrict__ fc1w, const float* __restrict__ fc1b,
             const float* __restrict__ fc2w, const float* __restrict__ fc2b,
             float* __restrict__ out)
{
    int b = blockIdx.x;
    int tid = threadIdx.x;
    __shared__ float hid[512];
    __shared__ float red[4];
    hid[tid]       = h1[b * H + tid];
    hid[256 + tid] = h1[(size_t)B * H + b * H + tid];
    __syncthreads();
    float a = fc1b[tid];
    const float4* w4 = (const float4*)(fc1w + tid * 512);
    const float4* h4 = (const float4*)hid;
    #pragma unroll 4
    for (int k = 0; k < 128; k++) {
        float4 w = w4[k], h = h4[k];
        a = fmaf(w.x, h.x, a); a = fmaf(w.y, h.y, a);
        a = fmaf(w.z, h.z, a); a = fmaf(w.w, h.w, a);
    }
    float r = fmaxf(a, 0.0f);
    float v = r * fc2w[tid];
    #pragma unroll
    for (int off = 32; off > 0; off >>= 1) v += __shfl_down(v, off, 64);
    if ((tid & 63) == 0) red[tid >> 6] = v;
    __syncthreads();
    if (tid == 0) out[b] = red[0] + red[1] + red[2] + red[3] + fc2b[0];
}

} // namespace

extern "C" void kernel_launch(void* const* d_in, const int* in_sizes, int n_in,
                              void* d_out, int out_size, void* d_ws, size_t ws_size,
                              hipStream_t stream)
{
    const float* x        = (const float*)d_in[0];
    const int*   lengths  = (const int*)d_in[1];
    const float* w_ih_l0f = (const float*)d_in[2];
    const float* w_hh_l0f = (const float*)d_in[3];
    const float* b_ih_l0f = (const float*)d_in[4];
    const float* b_hh_l0f = (const float*)d_in[5];
    const float* w_ih_l0b = (const float*)d_in[6];
    const float* w_hh_l0b = (const float*)d_in[7];
    const float* b_ih_l0b = (const float*)d_in[8];
    const float* b_hh_l0b = (const float*)d_in[9];
    const float* w_ih_l1f = (const float*)d_in[10];
    const float* w_hh_l1f = (const float*)d_in[11];
    const float* b_ih_l1f = (const float*)d_in[12];
    const float* b_hh_l1f = (const float*)d_in[13];
    const float* w_ih_l1b = (const float*)d_in[14];
    const float* w_hh_l1b = (const float*)d_in[15];
    const float* b_ih_l1b = (const float*)d_in[16];
    const float* b_hh_l1b = (const float*)d_in[17];
    const float* fc1w     = (const float*)d_in[18];
    const float* fc1b     = (const float*)d_in[19];
    const float* fc2w     = (const float*)d_in[20];
    const float* fc2b     = (const float*)d_in[21];

    float* ws = (float*)d_ws;

    // ---- workspace layout: [state | flags | O0] (no weight copies) ----
    float* state = ws;
    float* h_l0 = state;                        // [2 parity][2 dir][B][H]
    float* h_l1 = h_l0 + 4 * BH;
    float* c_l0 = h_l1 + 4 * BH;                // [2 dir][B][H]
    float* c_l1 = c_l0 + 2 * BH;
    int*   flags = (int*)(state + STATE_FLOATS);
    void*  O0   = (void*)(state + STATE_FLOATS + FLAG_INTS);

    const size_t base_bytes = (STATE_FLOATS + FLAG_INTS) * sizeof(float);
    const bool o0_f32 = ws_size >= base_bytes + O0_ELEMS * sizeof(float);

    // zero h/c state AND sync flags (ws is poisoned 0xAA before every call)
    zero_f<<<(int)((STATE_FLOATS + FLAG_INTS + 255) / 256), 256, 0, stream>>>(
        state, (int)(STATE_FLOATS + FLAG_INTS));

    if (o0_f32) {
        lstm_persist<float><<<256, NT, 0, stream>>>(
            x,
            w_ih_l0f, w_ih_l0b, w_hh_l0f, w_hh_l0b,
            b_ih_l0f, b_hh_l0f, b_ih_l0b, b_hh_l0b,
            w_ih_l1f, w_ih_l1b, w_hh_l1f, w_hh_l1b,
            b_ih_l1f, b_hh_l1f, b_ih_l1b, b_hh_l1b,
            h_l0, h_l1, c_l0, c_l1,
            (float*)O0, lengths, flags);
    } else {
        lstm_persist<unsigned short><<<256, NT, 0, stream>>>(
            x,
            w_ih_l0f, w_ih_l0b, w_hh_l0f, w_hh_l0b,
            b_ih_l0f, b_hh_l0f, b_ih_l0b, b_hh_l0b,
            w_ih_l1f, w_ih_l1b, w_hh_l1f, w_hh_l1b,
            b_ih_l1f, b_hh_l1f, b_ih_l1b, b_hh_l1b,
            h_l0, h_l1, c_l0, c_l1,
            (unsigned short*)O0, lengths, flags);
    }
    // FC head: T even -> final h lives at parity 0
    fc_head<<<B, 256, 0, stream>>>(h_l1, fc1w, fc1b, fc2w, fc2b, (float*)d_out);
}